// Round 17
// baseline (203.671 us; speedup 1.0000x reference)
//
#include <hip/hip_runtime.h>
#include <hip/hip_bf16.h>
#include <stdint.h>

#define T_TOK 8192
#define DIM   512
#define HID   1024
#define ODIM  512
#define NEXP  16
#define NSH   3

#define BM 128
#define BN 128
#define BK 64
#define MAXTILES 144
#define CAPSLOTS (MAXTILES * BM)

typedef __attribute__((ext_vector_type(8))) short s16x8;
typedef __attribute__((ext_vector_type(4))) float f32x4;

__device__ __forceinline__ uint16_t f2bf(float f) {
  union { float f; uint32_t u; } x; x.f = f;
  uint32_t r = x.u + 0x7FFFu + ((x.u >> 16) & 1u);
  return (uint16_t)(r >> 16);
}
__device__ __forceinline__ float bf2f(uint16_t u) {
  union { uint32_t u; float f; } x; x.u = ((uint32_t)u) << 16;
  return x.f;
}

__device__ __forceinline__ void async_copy16(const uint16_t* g, uint16_t* l) {
  __builtin_amdgcn_global_load_lds(
      (const __attribute__((address_space(1))) void*)g,
      (__attribute__((address_space(3))) void*)l, 16, 0, 0);
}

#define GTPB 16

// ---- shared 64x64 f32->bf16 transpose tile (pad-69 LDS) ----
__device__ __forceinline__ void transpose_tile(const float* __restrict__ src,
                                               uint16_t* __restrict__ dst,
                                               int K, int N, int ldk, int id,
                                               float (*tl)[69], int tid) {
  int ntn = N >> 6;
  int tile = id & 127;
  int n0 = (tile & (ntn - 1)) * 64, k0 = (tile / ntn) * 64;
  int lr = tid >> 4, lc = (tid & 15) * 4;
#pragma unroll
  for (int p = 0; p < 4; ++p) {
    int row = lr + p * 16;
    float4 v = *(const float4*)&src[(size_t)(k0 + row) * N + n0 + lc];
    tl[row][lc + 0] = v.x; tl[row][lc + 1] = v.y;
    tl[row][lc + 2] = v.z; tl[row][lc + 3] = v.w;
  }
  __syncthreads();
  int nr = tid >> 3, kc = (tid & 7) * 8;
#pragma unroll
  for (int p = 0; p < 2; ++p) {
    int n = nr + p * 32;
    s16x8 o;
#pragma unroll
    for (int j = 0; j < 8; ++j) o[j] = (short)f2bf(tl[kc + j][n]);
    *(s16x8*)&dst[(size_t)(n0 + n) * ldk + k0 + kc] = o;
  }
}

// ---- k_pre: ids 0..2431 = shw1/iw1 transposes; ids 2432..2943 = gating
//      (fp32 logits, top-2, fused x->bf16) + rowtok=-1 init.
//      The LAST gating block to finish (device-scope counter) runs schedfill:
//      histogram -> tdesc/ntl -> slot fill. ----
union PreSmem {
  float tl[64][69];
  struct { float xs[GTPB][516]; float gws[NEXP][516]; } g;
};

__global__ __launch_bounds__(256) void k_pre(
    const float* __restrict__ shw1, const float* __restrict__ iw1,
    uint16_t* __restrict__ shw1T, uint16_t* __restrict__ iw1T,
    const float* __restrict__ x, const float* __restrict__ gw,
    const float* __restrict__ gb, uint16_t* __restrict__ xb,
    int* __restrict__ tok_top, float* __restrict__ wgt_top,
    int* __restrict__ rowtok, int* __restrict__ done,
    int* __restrict__ tdesc, int* __restrict__ ntl,
    int* __restrict__ tok2slot) {
  __shared__ PreSmem sm;
  int tid = threadIdx.x;
  if (blockIdx.x < 2432) {
    int id = blockIdx.x;
    const float* src; uint16_t* dst;
    if (id < 384) { src = shw1; dst = shw1T; }
    else          { id -= 384; src = iw1; dst = iw1T; }
    int z = id >> 7;
    src += (size_t)z * 512 * 1024;
    dst += (size_t)z * HID * DIM;
    transpose_tile(src, dst, 512, 1024, 512, id, sm.tl, tid);
    return;
  }
  // ---------------- gating (+ rowtok init) ----------------
  int gb_id = blockIdx.x - 2432;
  int tb = gb_id * GTPB;
  if (tid < 36) rowtok[gb_id * 36 + tid] = -1;
#pragma unroll
  for (int it = 0; it < 8; ++it) {
    int idx = (it * 256 + tid) * 4;
    float4 v = *(const float4*)&gw[idx];
    int d = idx >> 4, e0 = idx & 15;
    sm.g.gws[e0 + 0][d] = v.x; sm.g.gws[e0 + 1][d] = v.y;
    sm.g.gws[e0 + 2][d] = v.z; sm.g.gws[e0 + 3][d] = v.w;
  }
#pragma unroll
  for (int it = 0; it < 8; ++it) {
    int idx = it * 1024 + tid * 4;
    float4 v = *(const float4*)&x[(size_t)tb * DIM + idx];
    *(float4*)&sm.g.xs[idx >> 9][idx & 511] = v;
  }
  __syncthreads();
#pragma unroll
  for (int it = 0; it < 4; ++it) {
    int idx = it * 2048 + tid * 8;
    int row = idx >> 9, col = idx & 511;
    float4 v0 = *(const float4*)&sm.g.xs[row][col];
    float4 v1 = *(const float4*)&sm.g.xs[row][col + 4];
    ushort4 o0, o1;
    o0.x = f2bf(v0.x); o0.y = f2bf(v0.y); o0.z = f2bf(v0.z); o0.w = f2bf(v0.w);
    o1.x = f2bf(v1.x); o1.y = f2bf(v1.y); o1.z = f2bf(v1.z); o1.w = f2bf(v1.w);
    *(ushort4*)&xb[(size_t)(tb + row) * DIM + col] = o0;
    *(ushort4*)&xb[(size_t)(tb + row) * DIM + col + 4] = o1;
  }
  int tok = tid >> 4, e = tid & 15;
  float acc = 0.f;
#pragma unroll 8
  for (int k = 0; k < DIM / 4; ++k) {
    float4 xv = *(const float4*)&sm.g.xs[tok][k * 4];
    float4 gv = *(const float4*)&sm.g.gws[e][k * 4];
    acc += xv.x * gv.x + xv.y * gv.y + xv.z * gv.z + xv.w * gv.w;
  }
  acc += gb[e];
  int lbase = (tid & 63) & 48;
  float best1 = -3.4e38f; int i1 = 0;
#pragma unroll
  for (int ee = 0; ee < NEXP; ++ee) {
    float v = __shfl(acc, lbase + ee, 64);
    if (v > best1) { best1 = v; i1 = ee; }
  }
  float best2 = -3.4e38f; int i2 = 0;
#pragma unroll
  for (int ee = 0; ee < NEXP; ++ee) {
    float v = __shfl(acc, lbase + ee, 64);
    if (ee != i1 && v > best2) { best2 = v; i2 = ee; }
  }
  if (e == 0) {
    int t = tb + tok;
    float w0 = 1.f / (1.f + expf(best2 - best1));
    tok_top[t * 2] = i1; tok_top[t * 2 + 1] = i2;
    wgt_top[t * 2] = w0; wgt_top[t * 2 + 1] = 1.f - w0;
  }
  // ---- last-gating-block-done: run schedfill ----
  __shared__ int s_last;
  __syncthreads();                 // all block stores complete (vmcnt drained)
  if (tid == 0) {
    __threadfence();               // release: make this block's stores visible
    int old = atomicAdd(done, 1);
    s_last = (old == 511);
  }
  __syncthreads();
  if (!s_last) return;
  __threadfence();                 // acquire: all 512 blocks' stores visible
  __shared__ int hist[NEXP], seoff[NEXP], sfill[NEXP];
  if (tid < NEXP) { hist[tid] = 0; sfill[tid] = 0; }
  __syncthreads();
  for (int i = tid; i < T_TOK * 2; i += 256) atomicAdd(&hist[tok_top[i]], 1);
  __syncthreads();
  if (tid == 0) {
    int o = 0, nt = 0;
    for (int ee = 0; ee < NEXP; ++ee) {
      seoff[ee] = o;
      int c = hist[ee];
      int t = (c + BM - 1) >> 7;
      for (int i = 0; i < t; ++i) { tdesc[nt * 2] = ee; tdesc[nt * 2 + 1] = o + i * BM; ++nt; }
      o += t << 7;
    }
    *ntl = nt;
  }
  __syncthreads();
  for (int t = tid; t < T_TOK; t += 256) {
#pragma unroll
    for (int k = 0; k < 2; ++k) {
      int ee = tok_top[t * 2 + k];
      int p = atomicAdd(&sfill[ee], 1);
      int slot = seoff[ee] + p;
      rowtok[slot] = t;
      tok2slot[t * 2 + k] = slot;
    }
  }
}

// -------- 128x128xK bf16 MFMA core: single-buffer global_load_lds + XOR swizzle --------
__device__ __forceinline__ void gemm_core(
    const uint16_t* a0, const uint16_t* a1, const uint16_t* a2, const uint16_t* a3,
    const uint16_t* b0, const uint16_t* b1, const uint16_t* b2, const uint16_t* b3,
    int nsteps, uint16_t* As, uint16_t* Bs, int wlds,
    int tl, int th, int wr, int wc, f32x4 (&acc)[4][4]) {
  const int sw = (tl & 7) << 3;
  for (int ks = 0; ks < nsteps; ++ks) {
    async_copy16(a0, As + wlds);           async_copy16(a1, As + wlds + 8 * BK);
    async_copy16(a2, As + wlds + 16 * BK); async_copy16(a3, As + wlds + 24 * BK);
    async_copy16(b0, Bs + wlds);           async_copy16(b1, Bs + wlds + 8 * BK);
    async_copy16(b2, Bs + wlds + 16 * BK); async_copy16(b3, Bs + wlds + 24 * BK);
    __syncthreads();
#pragma unroll
    for (int kk = 0; kk < 2; ++kk) {
      s16x8 af[4], bf[4];
#pragma unroll
      for (int i = 0; i < 4; ++i) {
        int eo = (kk * 32 + th * 8) ^ sw;
        af[i] = *(const s16x8*)&As[(wr * 64 + i * 16 + tl) * BK + eo];
        bf[i] = *(const s16x8*)&Bs[(wc * 64 + i * 16 + tl) * BK + eo];
      }
#pragma unroll
      for (int i = 0; i < 4; ++i)
#pragma unroll
        for (int j = 0; j < 4; ++j)
          acc[i][j] = __builtin_amdgcn_mfma_f32_16x16x32_bf16(af[i], bf[j], acc[i][j], 0, 0, 0);
    }
    __syncthreads();
    a0 += BK; a1 += BK; a2 += BK; a3 += BK;
    b0 += BK; b1 += BK; b2 += BK; b3 += BK;
  }
}

// ---- mega1: shared FFN1 (ids 0..1535) + ind FFN1 (ids 1536..2687)
//      + shw2/iw2 transposes for mega2 (ids 2688..5119, fill the drain tail). ----
union M1Smem {
  struct { uint16_t As[BM * BK]; uint16_t Bs[BN * BK]; } g;
  float tl[64][69];
};

__global__ __launch_bounds__(256) void k_mega1(
    const uint16_t* __restrict__ xb, const uint16_t* __restrict__ shw1T,
    const float* __restrict__ shb1, const float* __restrict__ obj,
    uint16_t* __restrict__ hbuf,
    const int* __restrict__ tdesc, const int* __restrict__ ntl,
    const int* __restrict__ rowtok, const uint16_t* __restrict__ iw1T,
    const float* __restrict__ ib1, uint16_t* __restrict__ hind,
    const float* __restrict__ shw2, const float* __restrict__ iw2,
    uint16_t* __restrict__ shw2T, uint16_t* __restrict__ iw2T) {
  __shared__ M1Smem sm;
  int id = blockIdx.x;
  int tid = threadIdx.x, lane = tid & 63, wid = tid >> 6;
  int wr = wid >> 1, wc = wid & 1, tl = lane & 15, th = lane >> 4;
  int lr = wid * 32 + (lane >> 3), koff = ((lane & 7) ^ (lane >> 3)) * 8;
  int wlds = wid * 32 * BK;
  if (id >= 2688) {
    int id2 = id - 2688;
    if (id2 < 384) {
      int z = id2 >> 7;
      transpose_tile(shw2 + (size_t)z * HID * ODIM, shw2T + (size_t)z * HID,
                     1024, 512, 3072, id2, sm.tl, tid);
    } else {
      id2 -= 384;
      int z = id2 >> 7;
      transpose_tile(iw2 + (size_t)z * HID * ODIM, iw2T + (size_t)z * ODIM * HID,
                     1024, 512, 1024, id2, sm.tl, tid);
    }
    return;
  }
  f32x4 acc[4][4] = {};
  if (id < 1536) {
    int xcd = id & 7, g = id >> 3;               // 8 xcd x 192
    int m0 = (xcd * 8 + g / 24) * BM;            // 8 m-tiles per xcd (1MB A in L2)
    int n0 = (g % 24) * BN;                      // n fast within the stripe
    const uint16_t* a0 = xb + (size_t)(m0 + lr) * DIM + koff;
    const uint16_t* b0 = shw1T + (size_t)(n0 + lr) * DIM + koff;
    gemm_core(a0, a0 + 8 * DIM, a0 + 16 * DIM, a0 + 24 * DIM,
              b0, b0 + 8 * DIM, b0 + 16 * DIM, b0 + 24 * DIM,
              DIM / BK, sm.g.As, sm.g.Bs, wlds, tl, th, wr, wc, acc);
#pragma unroll
    for (int i = 0; i < 4; ++i)
#pragma unroll
      for (int j = 0; j < 4; ++j) {
        int col = n0 + wc * 64 + j * 16 + tl;
        int s = col >> 10;
        float bv = shb1[col];
#pragma unroll
        for (int q = 0; q < 4; ++q) {
          int row = m0 + wr * 64 + i * 16 + th * 4 + q;
          float v = acc[i][j][q] + bv;
          float ow = 0.5f * obj[row * NSH + s];
          hbuf[(size_t)row * (NSH * HID) + col] = f2bf(ow * (v > 0.f ? v : 0.f));
        }
      }
  } else {
    int id2 = id - 1536;
    int xcd = id2 & 7, g = id2 >> 3;             // 8 xcd x 144
    int t = xcd * 18 + (g >> 3);                 // 18 expert-tiles per xcd
    int n0 = (g & 7) * BN;                       // n fastest: A panel reused
    if (t >= *ntl) return;
    int e = tdesc[t * 2], slot0 = tdesc[t * 2 + 1];
    const uint16_t* Bt = iw1T + (size_t)e * HID * DIM;
    const uint16_t* ap[4];
#pragma unroll
    for (int i = 0; i < 4; ++i) {
      int tk = rowtok[slot0 + lr + i * 8];
      if (tk < 0) tk = 0;
      ap[i] = xb + (size_t)tk * DIM + koff;
    }
    const uint16_t* b0 = Bt + (size_t)(n0 + lr) * DIM + koff;
    gemm_core(ap[0], ap[1], ap[2], ap[3],
              b0, b0 + 8 * DIM, b0 + 16 * DIM, b0 + 24 * DIM,
              DIM / BK, sm.g.As, sm.g.Bs, wlds, tl, th, wr, wc, acc);
#pragma unroll
    for (int i = 0; i < 4; ++i)
#pragma unroll
      for (int j = 0; j < 4; ++j) {
        int col = n0 + wc * 64 + j * 16 + tl;
        float bv = ib1[e * HID + col];
#pragma unroll
        for (int q = 0; q < 4; ++q) {
          int rowl = wr * 64 + i * 16 + th * 4 + q;
          float v = acc[i][j][q] + bv;
          hind[(size_t)(slot0 + rowl) * HID + col] = f2bf(v > 0.f ? v : 0.f);
        }
      }
  }
}

// ------- mega2: shared FFN2 K=3072 (ids 0..255, xcd-striped) + ind FFN2 (ids 256..831) -------
__global__ __launch_bounds__(256) void k_mega2(
    const uint16_t* __restrict__ hbuf, const uint16_t* __restrict__ shw2T,
    const float* __restrict__ shb2, const float* __restrict__ obj,
    float* __restrict__ outp,
    const int* __restrict__ tdesc, const int* __restrict__ ntl,
    const uint16_t* __restrict__ hind, const uint16_t* __restrict__ iw2T,
    const float* __restrict__ ib2,
    uint16_t* __restrict__ pind) {
  __shared__ uint16_t As[BM * BK], Bs[BN * BK];
  int id = blockIdx.x;
  int tid = threadIdx.x, lane = tid & 63, wid = tid >> 6;
  int wr = wid >> 1, wc = wid & 1, tl = lane & 15, th = lane >> 4;
  int lr = wid * 32 + (lane >> 3), koff = ((lane & 7) ^ (lane >> 3)) * 8;
  int wlds = wid * 32 * BK;
  f32x4 acc[4][4] = {};
  if (id < 256) {
    const int K = NSH * HID;
    int xcd = id & 7, g = id >> 3;               // 8 xcd x 32
    int m0 = (xcd * 8 + (g >> 2)) * BM;          // 8 m-tiles per xcd
    int n0 = (g & 3) * BN;                       // n fast: A row-panel reused
    const uint16_t* a0 = hbuf + (size_t)(m0 + lr) * K + koff;
    const uint16_t* b0 = shw2T + (size_t)(n0 + lr) * K + koff;
    gemm_core(a0, a0 + 8 * K, a0 + 16 * K, a0 + 24 * K,
              b0, b0 + 8 * K, b0 + 16 * K, b0 + 24 * K,
              K / BK, As, Bs, wlds, tl, th, wr, wc, acc);
#pragma unroll
    for (int i = 0; i < 4; ++i) {
      int rows[4]; float ob[4][NSH];
#pragma unroll
      for (int q = 0; q < 4; ++q) {
        rows[q] = m0 + wr * 64 + i * 16 + th * 4 + q;
#pragma unroll
        for (int s = 0; s < NSH; ++s) ob[q][s] = 0.5f * obj[rows[q] * NSH + s];
      }
#pragma unroll
      for (int j = 0; j < 4; ++j) {
        int col = n0 + wc * 64 + j * 16 + tl;
#pragma unroll
        for (int q = 0; q < 4; ++q) {
          float v = acc[i][j][q];
#pragma unroll
          for (int s = 0; s < NSH; ++s) v += ob[q][s] * shb2[s * ODIM + col];
          outp[(size_t)rows[q] * ODIM + col] = v;
        }
      }
    }
  } else {
    int id2 = id - 256;
    int xcd = id2 & 7, g = id2 >> 3;             // 8 xcd x 72: t(18) x n(4)
    int t = xcd * 18 + (g >> 2);
    int n0 = (g & 3) * BN;
    if (t >= *ntl) return;
    int e = tdesc[t * 2], slot0 = tdesc[t * 2 + 1];
    const uint16_t* a0 = hind + (size_t)(slot0 + lr) * HID + koff;
    const uint16_t* b0 = iw2T + (size_t)e * ODIM * HID + (size_t)(n0 + lr) * HID + koff;
    gemm_core(a0, a0 + 8 * HID, a0 + 16 * HID, a0 + 24 * HID,
              b0, b0 + 8 * HID, b0 + 16 * HID, b0 + 24 * HID,
              HID / BK, As, Bs, wlds, tl, th, wr, wc, acc);
#pragma unroll
    for (int i = 0; i < 4; ++i)
#pragma unroll
      for (int j = 0; j < 4; ++j) {
        int col = n0 + wc * 64 + j * 16 + tl;
        float bv = ib2[e * ODIM + col];
#pragma unroll
        for (int q = 0; q < 4; ++q) {
          int slot = slot0 + wr * 64 + i * 16 + th * 4 + q;
          pind[(size_t)slot * ODIM + col] = f2bf(acc[i][j][q] + bv);
        }
      }
  }
}

// -------- combine: out[t] += sum_k 0.5*w_k*pind[slot_k] --------
__global__ __launch_bounds__(256) void k_combine(float* __restrict__ outp,
                                                 const uint16_t* __restrict__ pind,
                                                 const int* __restrict__ tok2slot,
                                                 const float* __restrict__ wgt_top) {
  int t = blockIdx.x * 4 + (threadIdx.x >> 6);
  int c = (threadIdx.x & 63) * 8;
  int s0 = tok2slot[t * 2], s1 = tok2slot[t * 2 + 1];
  float w0 = 0.5f * wgt_top[t * 2], w1 = 0.5f * wgt_top[t * 2 + 1];
  s16x8 p0 = *(const s16x8*)&pind[(size_t)s0 * ODIM + c];
  s16x8 p1 = *(const s16x8*)&pind[(size_t)s1 * ODIM + c];
  float* op = &outp[(size_t)t * ODIM + c];
  float4 o0 = *(float4*)op, o1 = *(float4*)(op + 4);
  float r[8];
#pragma unroll
  for (int j = 0; j < 8; ++j)
    r[j] = w0 * bf2f((uint16_t)p0[j]) + w1 * bf2f((uint16_t)p1[j]);
  o0.x += r[0]; o0.y += r[1]; o0.z += r[2]; o0.w += r[3];
  o1.x += r[4]; o1.y += r[5]; o1.z += r[6]; o1.w += r[7];
  *(float4*)op = o0; *(float4*)(op + 4) = o1;
}

extern "C" void kernel_launch(void* const* d_in, const int* in_sizes, int n_in,
                              void* d_out, int out_size, void* d_ws, size_t ws_size,
                              hipStream_t stream) {
  (void)in_sizes; (void)n_in; (void)out_size; (void)ws_size;
  const float* fv   = (const float*)d_in[0];
  const float* obj  = (const float*)d_in[1];
  const float* gw   = (const float*)d_in[2];
  const float* gb   = (const float*)d_in[3];
  const float* shw1 = (const float*)d_in[4];
  const float* shb1 = (const float*)d_in[5];
  const float* shw2 = (const float*)d_in[6];
  const float* shb2 = (const float*)d_in[7];
  const float* iw1  = (const float*)d_in[8];
  const float* ib1  = (const float*)d_in[9];
  const float* iw2  = (const float*)d_in[10];
  const float* ib2  = (const float*)d_in[11];
  float* outp = (float*)d_out;

  char* w = (char*)d_ws;
  size_t off = 0;
  auto alloc = [&](size_t bytes) {
    char* p = w + off;
    off = (off + bytes + 255) & ~(size_t)255;
    return p;
  };
  uint16_t* xb    = (uint16_t*)alloc((size_t)T_TOK * DIM * 2);
  uint16_t* hbuf  = (uint16_t*)alloc((size_t)T_TOK * NSH * HID * 2);
  uint16_t* hind  = (uint16_t*)alloc((size_t)CAPSLOTS * HID * 2);
  uint16_t* pind  = (uint16_t*)alloc((size_t)CAPSLOTS * ODIM * 2);
  uint16_t* shw1T = (uint16_t*)alloc((size_t)NSH * HID * DIM * 2);
  uint16_t* shw2T = (uint16_t*)alloc((size_t)ODIM * NSH * HID * 2);
  uint16_t* iw1T  = (uint16_t*)alloc((size_t)NEXP * HID * DIM * 2);
  uint16_t* iw2T  = (uint16_t*)alloc((size_t)NEXP * ODIM * HID * 2);
  int*   tok_top  = (int*)alloc(T_TOK * 2 * 4);
  float* wgt_top  = (float*)alloc(T_TOK * 2 * 4);
  int*   tok2slot = (int*)alloc(T_TOK * 2 * 4);
  int*   rowtok   = (int*)alloc(CAPSLOTS * 4);
  int*   tdesc    = (int*)alloc(MAXTILES * 2 * 4);
  int*   ntl      = (int*)alloc(4);
  int*   done     = (int*)alloc(4);

  hipMemsetAsync(done, 0, 4, stream);
  k_pre<<<2944, 256, 0, stream>>>(shw1, iw1, shw1T, iw1T,
                                  fv, gw, gb, xb, tok_top, wgt_top, rowtok,
                                  done, tdesc, ntl, tok2slot);
  k_mega1<<<5120, 256, 0, stream>>>(
      xb, shw1T, shb1, obj, hbuf, tdesc, ntl, rowtok, iw1T, ib1, hind,
      shw2, iw2, shw2T, iw2T);
  k_mega2<<<256 + 4 * MAXTILES, 256, 0, stream>>>(
      hbuf, shw2T, shb2, obj, outp, tdesc, ntl, hind, iw2T, ib2, pind);
  k_combine<<<T_TOK / 4, 256, 0, stream>>>(outp, pind, tok2slot, wgt_top);
}

// Round 18
// 196.810 us; speedup vs baseline: 1.0349x; 1.0349x over previous
//
#include <hip/hip_runtime.h>
#include <hip/hip_bf16.h>
#include <stdint.h>

#define T_TOK 8192
#define DIM   512
#define HID   1024
#define ODIM  512
#define NEXP  16
#define NSH   3

#define BM 128
#define BN 128
#define BK 64
#define MAXTILES 144
#define CAPSLOTS (MAXTILES * BM)

typedef __attribute__((ext_vector_type(8))) short s16x8;
typedef __attribute__((ext_vector_type(4))) float f32x4;

__device__ __forceinline__ uint16_t f2bf(float f) {
  union { float f; uint32_t u; } x; x.f = f;
  uint32_t r = x.u + 0x7FFFu + ((x.u >> 16) & 1u);
  return (uint16_t)(r >> 16);
}
__device__ __forceinline__ float bf2f(uint16_t u) {
  union { uint32_t u; float f; } x; x.u = ((uint32_t)u) << 16;
  return x.f;
}

__device__ __forceinline__ void async_copy16(const uint16_t* g, uint16_t* l) {
  __builtin_amdgcn_global_load_lds(
      (const __attribute__((address_space(1))) void*)g,
      (__attribute__((address_space(3))) void*)l, 16, 0, 0);
}

#define GTPB 16

// ---- shared 64x64 f32->bf16 transpose tile (pad-69 LDS) ----
__device__ __forceinline__ void transpose_tile(const float* __restrict__ src,
                                               uint16_t* __restrict__ dst,
                                               int K, int N, int ldk, int id,
                                               float (*tl)[69], int tid) {
  int ntn = N >> 6;
  int tile = id & 127;
  int n0 = (tile & (ntn - 1)) * 64, k0 = (tile / ntn) * 64;
  int lr = tid >> 4, lc = (tid & 15) * 4;
#pragma unroll
  for (int p = 0; p < 4; ++p) {
    int row = lr + p * 16;
    float4 v = *(const float4*)&src[(size_t)(k0 + row) * N + n0 + lc];
    tl[row][lc + 0] = v.x; tl[row][lc + 1] = v.y;
    tl[row][lc + 2] = v.z; tl[row][lc + 3] = v.w;
  }
  __syncthreads();
  int nr = tid >> 3, kc = (tid & 7) * 8;
#pragma unroll
  for (int p = 0; p < 2; ++p) {
    int n = nr + p * 32;
    s16x8 o;
#pragma unroll
    for (int j = 0; j < 8; ++j) o[j] = (short)f2bf(tl[kc + j][n]);
    *(s16x8*)&dst[(size_t)(n0 + n) * ldk + k0 + kc] = o;
  }
}

// ---- k_pre: ids 0..2431 = shw1/iw1 transposes; ids 2432..2943 = gating
//      (fp32 logits, top-2, fused x->bf16) + rowtok=-1 init. ----
union PreSmem {
  float tl[64][69];
  struct { float xs[GTPB][516]; float gws[NEXP][516]; } g;
};

__global__ __launch_bounds__(256) void k_pre(
    const float* __restrict__ shw1, const float* __restrict__ iw1,
    uint16_t* __restrict__ shw1T, uint16_t* __restrict__ iw1T,
    const float* __restrict__ x, const float* __restrict__ gw,
    const float* __restrict__ gb, uint16_t* __restrict__ xb,
    int* __restrict__ tok_top, float* __restrict__ wgt_top,
    int* __restrict__ rowtok) {
  __shared__ PreSmem sm;
  int tid = threadIdx.x;
  if (blockIdx.x < 2432) {
    int id = blockIdx.x;
    const float* src; uint16_t* dst;
    if (id < 384) { src = shw1; dst = shw1T; }
    else          { id -= 384; src = iw1; dst = iw1T; }
    int z = id >> 7;
    src += (size_t)z * 512 * 1024;
    dst += (size_t)z * HID * DIM;
    transpose_tile(src, dst, 512, 1024, 512, id, sm.tl, tid);
  } else {
    // ---------------- gating (+ rowtok init) ----------------
    int gb_id = blockIdx.x - 2432;
    int tb = gb_id * GTPB;
    if (tid < 36) rowtok[gb_id * 36 + tid] = -1;
#pragma unroll
    for (int it = 0; it < 8; ++it) {
      int idx = (it * 256 + tid) * 4;
      float4 v = *(const float4*)&gw[idx];
      int d = idx >> 4, e0 = idx & 15;
      sm.g.gws[e0 + 0][d] = v.x; sm.g.gws[e0 + 1][d] = v.y;
      sm.g.gws[e0 + 2][d] = v.z; sm.g.gws[e0 + 3][d] = v.w;
    }
#pragma unroll
    for (int it = 0; it < 8; ++it) {
      int idx = it * 1024 + tid * 4;
      float4 v = *(const float4*)&x[(size_t)tb * DIM + idx];
      *(float4*)&sm.g.xs[idx >> 9][idx & 511] = v;
    }
    __syncthreads();
#pragma unroll
    for (int it = 0; it < 4; ++it) {
      int idx = it * 2048 + tid * 8;
      int row = idx >> 9, col = idx & 511;
      float4 v0 = *(const float4*)&sm.g.xs[row][col];
      float4 v1 = *(const float4*)&sm.g.xs[row][col + 4];
      ushort4 o0, o1;
      o0.x = f2bf(v0.x); o0.y = f2bf(v0.y); o0.z = f2bf(v0.z); o0.w = f2bf(v0.w);
      o1.x = f2bf(v1.x); o1.y = f2bf(v1.y); o1.z = f2bf(v1.z); o1.w = f2bf(v1.w);
      *(ushort4*)&xb[(size_t)(tb + row) * DIM + col] = o0;
      *(ushort4*)&xb[(size_t)(tb + row) * DIM + col + 4] = o1;
    }
    int tok = tid >> 4, e = tid & 15;
    float acc = 0.f;
#pragma unroll 8
    for (int k = 0; k < DIM / 4; ++k) {
      float4 xv = *(const float4*)&sm.g.xs[tok][k * 4];
      float4 gv = *(const float4*)&sm.g.gws[e][k * 4];
      acc += xv.x * gv.x + xv.y * gv.y + xv.z * gv.z + xv.w * gv.w;
    }
    acc += gb[e];
    int lbase = (tid & 63) & 48;
    float best1 = -3.4e38f; int i1 = 0;
#pragma unroll
    for (int ee = 0; ee < NEXP; ++ee) {
      float v = __shfl(acc, lbase + ee, 64);
      if (v > best1) { best1 = v; i1 = ee; }
    }
    float best2 = -3.4e38f; int i2 = 0;
#pragma unroll
    for (int ee = 0; ee < NEXP; ++ee) {
      float v = __shfl(acc, lbase + ee, 64);
      if (ee != i1 && v > best2) { best2 = v; i2 = ee; }
    }
    if (e == 0) {
      int t = tb + tok;
      float w0 = 1.f / (1.f + expf(best2 - best1));
      tok_top[t * 2] = i1; tok_top[t * 2 + 1] = i2;
      wgt_top[t * 2] = w0; wgt_top[t * 2 + 1] = 1.f - w0;
    }
  }
}

// ---- k_schedfill (1 block): histogram tok_top -> tdesc/ntl -> fill slots ----
__global__ __launch_bounds__(256) void k_schedfill(
    const int* __restrict__ tok_top,
    int* __restrict__ tdesc, int* __restrict__ ntl,
    int* __restrict__ rowtok, int* __restrict__ tok2slot) {
  __shared__ int hist[NEXP], seoff[NEXP], sfill[NEXP];
  int tid = threadIdx.x;
  if (tid < NEXP) { hist[tid] = 0; sfill[tid] = 0; }
  __syncthreads();
  for (int i = tid; i < T_TOK * 2; i += 256) atomicAdd(&hist[tok_top[i]], 1);
  __syncthreads();
  if (tid == 0) {
    int o = 0, nt = 0;
    for (int e = 0; e < NEXP; ++e) {
      seoff[e] = o;
      int c = hist[e];
      int t = (c + BM - 1) >> 7;
      for (int i = 0; i < t; ++i) { tdesc[nt * 2] = e; tdesc[nt * 2 + 1] = o + i * BM; ++nt; }
      o += t << 7;
    }
    *ntl = nt;
  }
  __syncthreads();
  for (int t = tid; t < T_TOK; t += 256) {
#pragma unroll
    for (int k = 0; k < 2; ++k) {
      int e = tok_top[t * 2 + k];
      int p = atomicAdd(&sfill[e], 1);
      int slot = seoff[e] + p;
      rowtok[slot] = t;
      tok2slot[t * 2 + k] = slot;
    }
  }
}

// -------- 128x128xK bf16 MFMA core: single-buffer global_load_lds + XOR swizzle --------
__device__ __forceinline__ void gemm_core(
    const uint16_t* a0, const uint16_t* a1, const uint16_t* a2, const uint16_t* a3,
    const uint16_t* b0, const uint16_t* b1, const uint16_t* b2, const uint16_t* b3,
    int nsteps, uint16_t* As, uint16_t* Bs, int wlds,
    int tl, int th, int wr, int wc, f32x4 (&acc)[4][4]) {
  const int sw = (tl & 7) << 3;
  for (int ks = 0; ks < nsteps; ++ks) {
    async_copy16(a0, As + wlds);           async_copy16(a1, As + wlds + 8 * BK);
    async_copy16(a2, As + wlds + 16 * BK); async_copy16(a3, As + wlds + 24 * BK);
    async_copy16(b0, Bs + wlds);           async_copy16(b1, Bs + wlds + 8 * BK);
    async_copy16(b2, Bs + wlds + 16 * BK); async_copy16(b3, Bs + wlds + 24 * BK);
    __syncthreads();
#pragma unroll
    for (int kk = 0; kk < 2; ++kk) {
      s16x8 af[4], bf[4];
#pragma unroll
      for (int i = 0; i < 4; ++i) {
        int eo = (kk * 32 + th * 8) ^ sw;
        af[i] = *(const s16x8*)&As[(wr * 64 + i * 16 + tl) * BK + eo];
        bf[i] = *(const s16x8*)&Bs[(wc * 64 + i * 16 + tl) * BK + eo];
      }
#pragma unroll
      for (int i = 0; i < 4; ++i)
#pragma unroll
        for (int j = 0; j < 4; ++j)
          acc[i][j] = __builtin_amdgcn_mfma_f32_16x16x32_bf16(af[i], bf[j], acc[i][j], 0, 0, 0);
    }
    __syncthreads();
    a0 += BK; a1 += BK; a2 += BK; a3 += BK;
    b0 += BK; b1 += BK; b2 += BK; b3 += BK;
  }
}

// ---- mega1: shared FFN1 (ids 0..1535) + ind FFN1 (ids 1536..2687)
//      + shw2/iw2 transposes for mega2 (ids 2688..5119, fill the drain tail). ----
union M1Smem {
  struct { uint16_t As[BM * BK]; uint16_t Bs[BN * BK]; } g;
  float tl[64][69];
};

__global__ __launch_bounds__(256) void k_mega1(
    const uint16_t* __restrict__ xb, const uint16_t* __restrict__ shw1T,
    const float* __restrict__ shb1, const float* __restrict__ obj,
    uint16_t* __restrict__ hbuf,
    const int* __restrict__ tdesc, const int* __restrict__ ntl,
    const int* __restrict__ rowtok, const uint16_t* __restrict__ iw1T,
    const float* __restrict__ ib1, uint16_t* __restrict__ hind,
    const float* __restrict__ shw2, const float* __restrict__ iw2,
    uint16_t* __restrict__ shw2T, uint16_t* __restrict__ iw2T) {
  __shared__ M1Smem sm;
  int id = blockIdx.x;
  int tid = threadIdx.x, lane = tid & 63, wid = tid >> 6;
  int wr = wid >> 1, wc = wid & 1, tl = lane & 15, th = lane >> 4;
  int lr = wid * 32 + (lane >> 3), koff = ((lane & 7) ^ (lane >> 3)) * 8;
  int wlds = wid * 32 * BK;
  if (id >= 2688) {
    int id2 = id - 2688;
    if (id2 < 384) {
      int z = id2 >> 7;
      transpose_tile(shw2 + (size_t)z * HID * ODIM, shw2T + (size_t)z * HID,
                     1024, 512, 3072, id2, sm.tl, tid);
    } else {
      id2 -= 384;
      int z = id2 >> 7;
      transpose_tile(iw2 + (size_t)z * HID * ODIM, iw2T + (size_t)z * ODIM * HID,
                     1024, 512, 1024, id2, sm.tl, tid);
    }
    return;
  }
  f32x4 acc[4][4] = {};
  if (id < 1536) {
    int xcd = id & 7, g = id >> 3;               // 8 xcd x 192
    int m0 = (xcd * 8 + g / 24) * BM;            // 8 m-tiles per xcd (1MB A in L2)
    int n0 = (g % 24) * BN;                      // n fast within the stripe
    const uint16_t* a0 = xb + (size_t)(m0 + lr) * DIM + koff;
    const uint16_t* b0 = shw1T + (size_t)(n0 + lr) * DIM + koff;
    gemm_core(a0, a0 + 8 * DIM, a0 + 16 * DIM, a0 + 24 * DIM,
              b0, b0 + 8 * DIM, b0 + 16 * DIM, b0 + 24 * DIM,
              DIM / BK, sm.g.As, sm.g.Bs, wlds, tl, th, wr, wc, acc);
#pragma unroll
    for (int i = 0; i < 4; ++i)
#pragma unroll
      for (int j = 0; j < 4; ++j) {
        int col = n0 + wc * 64 + j * 16 + tl;
        int s = col >> 10;
        float bv = shb1[col];
#pragma unroll
        for (int q = 0; q < 4; ++q) {
          int row = m0 + wr * 64 + i * 16 + th * 4 + q;
          float v = acc[i][j][q] + bv;
          float ow = 0.5f * obj[row * NSH + s];
          hbuf[(size_t)row * (NSH * HID) + col] = f2bf(ow * (v > 0.f ? v : 0.f));
        }
      }
  } else {
    int id2 = id - 1536;
    int xcd = id2 & 7, g = id2 >> 3;             // 8 xcd x 144
    int t = xcd * 18 + (g >> 3);                 // 18 expert-tiles per xcd
    int n0 = (g & 7) * BN;                       // n fastest: A panel reused
    if (t >= *ntl) return;
    int e = tdesc[t * 2], slot0 = tdesc[t * 2 + 1];
    const uint16_t* Bt = iw1T + (size_t)e * HID * DIM;
    const uint16_t* ap[4];
#pragma unroll
    for (int i = 0; i < 4; ++i) {
      int tk = rowtok[slot0 + lr + i * 8];
      if (tk < 0) tk = 0;
      ap[i] = xb + (size_t)tk * DIM + koff;
    }
    const uint16_t* b0 = Bt + (size_t)(n0 + lr) * DIM + koff;
    gemm_core(ap[0], ap[1], ap[2], ap[3],
              b0, b0 + 8 * DIM, b0 + 16 * DIM, b0 + 24 * DIM,
              DIM / BK, sm.g.As, sm.g.Bs, wlds, tl, th, wr, wc, acc);
#pragma unroll
    for (int i = 0; i < 4; ++i)
#pragma unroll
      for (int j = 0; j < 4; ++j) {
        int col = n0 + wc * 64 + j * 16 + tl;
        float bv = ib1[e * HID + col];
#pragma unroll
        for (int q = 0; q < 4; ++q) {
          int rowl = wr * 64 + i * 16 + th * 4 + q;
          float v = acc[i][j][q] + bv;
          hind[(size_t)(slot0 + rowl) * HID + col] = f2bf(v > 0.f ? v : 0.f);
        }
      }
  }
}

// ------- mega2: shared FFN2 K=3072 (ids 0..255, xcd-striped) + ind FFN2 (ids 256..831) -------
__global__ __launch_bounds__(256) void k_mega2(
    const uint16_t* __restrict__ hbuf, const uint16_t* __restrict__ shw2T,
    const float* __restrict__ shb2, const float* __restrict__ obj,
    float* __restrict__ outp,
    const int* __restrict__ tdesc, const int* __restrict__ ntl,
    const uint16_t* __restrict__ hind, const uint16_t* __restrict__ iw2T,
    const float* __restrict__ ib2,
    uint16_t* __restrict__ pind) {
  __shared__ uint16_t As[BM * BK], Bs[BN * BK];
  int id = blockIdx.x;
  int tid = threadIdx.x, lane = tid & 63, wid = tid >> 6;
  int wr = wid >> 1, wc = wid & 1, tl = lane & 15, th = lane >> 4;
  int lr = wid * 32 + (lane >> 3), koff = ((lane & 7) ^ (lane >> 3)) * 8;
  int wlds = wid * 32 * BK;
  f32x4 acc[4][4] = {};
  if (id < 256) {
    const int K = NSH * HID;
    int xcd = id & 7, g = id >> 3;               // 8 xcd x 32
    int m0 = (xcd * 8 + (g >> 2)) * BM;          // 8 m-tiles per xcd
    int n0 = (g & 3) * BN;                       // n fast: A row-panel reused
    const uint16_t* a0 = hbuf + (size_t)(m0 + lr) * K + koff;
    const uint16_t* b0 = shw2T + (size_t)(n0 + lr) * K + koff;
    gemm_core(a0, a0 + 8 * K, a0 + 16 * K, a0 + 24 * K,
              b0, b0 + 8 * K, b0 + 16 * K, b0 + 24 * K,
              K / BK, As, Bs, wlds, tl, th, wr, wc, acc);
#pragma unroll
    for (int i = 0; i < 4; ++i) {
      int rows[4]; float ob[4][NSH];
#pragma unroll
      for (int q = 0; q < 4; ++q) {
        rows[q] = m0 + wr * 64 + i * 16 + th * 4 + q;
#pragma unroll
        for (int s = 0; s < NSH; ++s) ob[q][s] = 0.5f * obj[rows[q] * NSH + s];
      }
#pragma unroll
      for (int j = 0; j < 4; ++j) {
        int col = n0 + wc * 64 + j * 16 + tl;
#pragma unroll
        for (int q = 0; q < 4; ++q) {
          float v = acc[i][j][q];
#pragma unroll
          for (int s = 0; s < NSH; ++s) v += ob[q][s] * shb2[s * ODIM + col];
          outp[(size_t)rows[q] * ODIM + col] = v;
        }
      }
    }
  } else {
    int id2 = id - 256;
    int xcd = id2 & 7, g = id2 >> 3;             // 8 xcd x 72: t(18) x n(4)
    int t = xcd * 18 + (g >> 2);
    int n0 = (g & 3) * BN;
    if (t >= *ntl) return;
    int e = tdesc[t * 2], slot0 = tdesc[t * 2 + 1];
    const uint16_t* a0 = hind + (size_t)(slot0 + lr) * HID + koff;
    const uint16_t* b0 = iw2T + (size_t)e * ODIM * HID + (size_t)(n0 + lr) * HID + koff;
    gemm_core(a0, a0 + 8 * HID, a0 + 16 * HID, a0 + 24 * HID,
              b0, b0 + 8 * HID, b0 + 16 * HID, b0 + 24 * HID,
              HID / BK, As, Bs, wlds, tl, th, wr, wc, acc);
#pragma unroll
    for (int i = 0; i < 4; ++i)
#pragma unroll
      for (int j = 0; j < 4; ++j) {
        int col = n0 + wc * 64 + j * 16 + tl;
        float bv = ib2[e * ODIM + col];
#pragma unroll
        for (int q = 0; q < 4; ++q) {
          int slot = slot0 + wr * 64 + i * 16 + th * 4 + q;
          pind[(size_t)slot * ODIM + col] = f2bf(acc[i][j][q] + bv);
        }
      }
  }
}

// -------- combine: out[t] += sum_k 0.5*w_k*pind[slot_k] --------
__global__ __launch_bounds__(256) void k_combine(float* __restrict__ outp,
                                                 const uint16_t* __restrict__ pind,
                                                 const int* __restrict__ tok2slot,
                                                 const float* __restrict__ wgt_top) {
  int t = blockIdx.x * 4 + (threadIdx.x >> 6);
  int c = (threadIdx.x & 63) * 8;
  int s0 = tok2slot[t * 2], s1 = tok2slot[t * 2 + 1];
  float w0 = 0.5f * wgt_top[t * 2], w1 = 0.5f * wgt_top[t * 2 + 1];
  s16x8 p0 = *(const s16x8*)&pind[(size_t)s0 * ODIM + c];
  s16x8 p1 = *(const s16x8*)&pind[(size_t)s1 * ODIM + c];
  float* op = &outp[(size_t)t * ODIM + c];
  float4 o0 = *(float4*)op, o1 = *(float4*)(op + 4);
  float r[8];
#pragma unroll
  for (int j = 0; j < 8; ++j)
    r[j] = w0 * bf2f((uint16_t)p0[j]) + w1 * bf2f((uint16_t)p1[j]);
  o0.x += r[0]; o0.y += r[1]; o0.z += r[2]; o0.w += r[3];
  o1.x += r[4]; o1.y += r[5]; o1.z += r[6]; o1.w += r[7];
  *(float4*)op = o0; *(float4*)(op + 4) = o1;
}

extern "C" void kernel_launch(void* const* d_in, const int* in_sizes, int n_in,
                              void* d_out, int out_size, void* d_ws, size_t ws_size,
                              hipStream_t stream) {
  (void)in_sizes; (void)n_in; (void)out_size; (void)ws_size;
  const float* fv   = (const float*)d_in[0];
  const float* obj  = (const float*)d_in[1];
  const float* gw   = (const float*)d_in[2];
  const float* gb   = (const float*)d_in[3];
  const float* shw1 = (const float*)d_in[4];
  const float* shb1 = (const float*)d_in[5];
  const float* shw2 = (const float*)d_in[6];
  const float* shb2 = (const float*)d_in[7];
  const float* iw1  = (const float*)d_in[8];
  const float* ib1  = (const float*)d_in[9];
  const float* iw2  = (const float*)d_in[10];
  const float* ib2  = (const float*)d_in[11];
  float* outp = (float*)d_out;

  char* w = (char*)d_ws;
  size_t off = 0;
  auto alloc = [&](size_t bytes) {
    char* p = w + off;
    off = (off + bytes + 255) & ~(size_t)255;
    return p;
  };
  uint16_t* xb    = (uint16_t*)alloc((size_t)T_TOK * DIM * 2);
  uint16_t* hbuf  = (uint16_t*)alloc((size_t)T_TOK * NSH * HID * 2);
  uint16_t* hind  = (uint16_t*)alloc((size_t)CAPSLOTS * HID * 2);
  uint16_t* pind  = (uint16_t*)alloc((size_t)CAPSLOTS * ODIM * 2);
  uint16_t* shw1T = (uint16_t*)alloc((size_t)NSH * HID * DIM * 2);
  uint16_t* shw2T = (uint16_t*)alloc((size_t)ODIM * NSH * HID * 2);
  uint16_t* iw1T  = (uint16_t*)alloc((size_t)NEXP * HID * DIM * 2);
  uint16_t* iw2T  = (uint16_t*)alloc((size_t)NEXP * ODIM * HID * 2);
  int*   tok_top  = (int*)alloc(T_TOK * 2 * 4);
  float* wgt_top  = (float*)alloc(T_TOK * 2 * 4);
  int*   tok2slot = (int*)alloc(T_TOK * 2 * 4);
  int*   rowtok   = (int*)alloc(CAPSLOTS * 4);
  int*   tdesc    = (int*)alloc(MAXTILES * 2 * 4);
  int*   ntl      = (int*)alloc(4);

  k_pre<<<2944, 256, 0, stream>>>(shw1, iw1, shw1T, iw1T,
                                  fv, gw, gb, xb, tok_top, wgt_top, rowtok);
  k_schedfill<<<1, 256, 0, stream>>>(tok_top, tdesc, ntl, rowtok, tok2slot);

  k_mega1<<<5120, 256, 0, stream>>>(
      xb, shw1T, shb1, obj, hbuf, tdesc, ntl, rowtok, iw1T, ib1, hind,
      shw2, iw2, shw2T, iw2T);
  k_mega2<<<256 + 4 * MAXTILES, 256, 0, stream>>>(
      hbuf, shw2T, shb2, obj, outp, tdesc, ntl, hind, iw2T, ib2, pind);
  k_combine<<<T_TOK / 4, 256, 0, stream>>>(outp, pind, tok2slot, wgt_top);
}